// Round 8
// baseline (318.636 us; speedup 1.0000x reference)
//
#include <hip/hip_runtime.h>

#define S_LEN 512
#define BATCH 64
#define HDIM  1024
#define TWOH  2048
#define EMB   512
#define KDIM  2560      // 2H + EMB
#define VOUT  32000

// ws layout (float offsets)
#define WS_MS    64
#define WS_CTX   2112
#define WS_GP    WS_CTX                      // gate partials [4][4096][64] alias dead ctx region
#define WS_RNNT  (WS_CTX + 64*16*2048)       // 2,099,264
#define WS_HIDT  (WS_RNNT + KDIM*64)         // 2,263,104
#define WS_HT    (WS_HIDT + HDIM*64)         // 2,328,640

__device__ __forceinline__ float sigmoidf_(float x) { return 1.f/(1.f+__expf(-x)); }

// K1 v3: single-pass online-softmax context, row-pipelined, hb inline.
__global__ __launch_bounds__(256) void k_attn(const float* __restrict__ enc,
                                              const float* __restrict__ eW,
                                              const float* __restrict__ eb,
                                              const float* __restrict__ hidden,
                                              float* __restrict__ ws_ms,
                                              float* __restrict__ ws_ctx) {
  __shared__ float lds_ms[4][2];
  __shared__ float lds_ctx[4][2048];
  const int lane  = threadIdx.x & 63;
  const int wave  = threadIdx.x >> 6;
  const int chunk = blockIdx.x;   // 0..15
  const int b     = blockIdx.y;   // 0..63

  float hba = 0.f;
  for (int k = lane; k < HDIM; k += 64) hba += hidden[b*HDIM + k] * eW[k];
#pragma unroll
  for (int st = 32; st >= 1; st >>= 1) hba += __shfl_xor(hba, st, 64);
  const float hb = hba + eb[0];

  float4 w4[8];
#pragma unroll
  for (int k = 0; k < 8; ++k)
    w4[k] = *reinterpret_cast<const float4*>(eW + HDIM + 4*lane + 256*k);

  const int s0 = chunk*32 + wave*8;
  const float* base = enc + ((size_t)(s0*BATCH + b))*TWOH + 4*lane;

  float m = 0.f, ssum = 0.f;      // relu => e >= 0
  float4 ctx[8];
#pragma unroll
  for (int k = 0; k < 8; ++k) ctx[k] = make_float4(0.f, 0.f, 0.f, 0.f);

  float4 va[8], vb[8];
#pragma unroll
  for (int k = 0; k < 8; ++k) va[k] = *reinterpret_cast<const float4*>(base + 256*k);

#define ATTN_STEP(VCUR, VNXT, I)                                              \
  {                                                                           \
    if ((I) < 7) {                                                            \
      const float* pn = base + (size_t)((I)+1)*BATCH*TWOH;                    \
      _Pragma("unroll")                                                       \
      for (int k = 0; k < 8; ++k)                                             \
        VNXT[k] = *reinterpret_cast<const float4*>(pn + 256*k);               \
    }                                                                         \
    float a = 0.f;                                                            \
    _Pragma("unroll")                                                         \
    for (int k = 0; k < 8; ++k)                                               \
      a += VCUR[k].x*w4[k].x + VCUR[k].y*w4[k].y +                            \
           VCUR[k].z*w4[k].z + VCUR[k].w*w4[k].w;                             \
    _Pragma("unroll")                                                         \
    for (int st = 1; st < 64; st <<= 1) a += __shfl_xor(a, st, 64);           \
    const float e = fmaxf(a + hb, 0.f);                                       \
    if (e > m) {                                                              \
      const float sc = __expf(m - e);                                         \
      ssum = ssum*sc + 1.f;                                                   \
      _Pragma("unroll")                                                       \
      for (int k = 0; k < 8; ++k) {                                           \
        ctx[k].x = fmaf(ctx[k].x, sc, VCUR[k].x);                             \
        ctx[k].y = fmaf(ctx[k].y, sc, VCUR[k].y);                             \
        ctx[k].z = fmaf(ctx[k].z, sc, VCUR[k].z);                             \
        ctx[k].w = fmaf(ctx[k].w, sc, VCUR[k].w);                             \
      }                                                                       \
      m = e;                                                                  \
    } else {                                                                  \
      const float pw = __expf(e - m);                                         \
      ssum += pw;                                                             \
      _Pragma("unroll")                                                       \
      for (int k = 0; k < 8; ++k) {                                           \
        ctx[k].x = fmaf(pw, VCUR[k].x, ctx[k].x);                             \
        ctx[k].y = fmaf(pw, VCUR[k].y, ctx[k].y);                             \
        ctx[k].z = fmaf(pw, VCUR[k].z, ctx[k].z);                             \
        ctx[k].w = fmaf(pw, VCUR[k].w, ctx[k].w);                             \
      }                                                                       \
    }                                                                         \
  }

  ATTN_STEP(va, vb, 0)
  ATTN_STEP(vb, va, 1)
  ATTN_STEP(va, vb, 2)
  ATTN_STEP(vb, va, 3)
  ATTN_STEP(va, vb, 4)
  ATTN_STEP(vb, va, 5)
  ATTN_STEP(va, vb, 6)
  ATTN_STEP(vb, va, 7)
#undef ATTN_STEP

  if (lane == 0) { lds_ms[wave][0] = m; lds_ms[wave][1] = ssum; }
  __syncthreads();
  const float M = fmaxf(fmaxf(lds_ms[0][0], lds_ms[1][0]),
                        fmaxf(lds_ms[2][0], lds_ms[3][0]));
  const float wsc = __expf(m - M);
  float ssum_c = 0.f;
#pragma unroll
  for (int w = 0; w < 4; ++w) ssum_c += __expf(lds_ms[w][0] - M) * lds_ms[w][1];
#pragma unroll
  for (int k = 0; k < 8; ++k) {
    float4 c = ctx[k];
    c.x *= wsc; c.y *= wsc; c.z *= wsc; c.w *= wsc;
    *reinterpret_cast<float4*>(&lds_ctx[wave][4*lane + 256*k]) = c;
  }
  __syncthreads();
  float* outp = ws_ctx + ((size_t)b*16 + chunk)*TWOH;
  for (int d = threadIdx.x; d < TWOH; d += 256)
    outp[d] = lds_ctx[0][d] + lds_ctx[1][d] + lds_ctx[2][d] + lds_ctx[3][d];
  if (threadIdx.x == 0) {
    ws_ms[((size_t)b*16 + chunk)*2]     = M;
    ws_ms[((size_t)b*16 + chunk)*2 + 1] = ssum_c;
  }
}

// K2: combine 16 chunk-partials per b; build transposed rnn input + hidden.
__global__ __launch_bounds__(256) void k_combine(const float* __restrict__ ws_ms,
                                                 const float* __restrict__ ws_ctx,
                                                 const float* __restrict__ hidden,
                                                 const float* __restrict__ emb_table,
                                                 const int* __restrict__ x,
                                                 float* __restrict__ ws_rnnT,
                                                 float* __restrict__ ws_hidT) {
  const int b = blockIdx.x;
  float mc[16], sc[16];
#pragma unroll
  for (int c = 0; c < 16; ++c) {
    mc[c] = ws_ms[(b*16 + c)*2];
    sc[c] = ws_ms[(b*16 + c)*2 + 1];
  }
  float M = mc[0];
#pragma unroll
  for (int c = 1; c < 16; ++c) M = fmaxf(M, mc[c]);
  float wc[16], Ssum = 0.f;
#pragma unroll
  for (int c = 0; c < 16; ++c) { wc[c] = __expf(mc[c] - M); Ssum += wc[c]*sc[c]; }
  const float inv = 1.f / Ssum;
  for (int d = threadIdx.x; d < TWOH; d += 256) {
    float a = 0.f;
#pragma unroll
    for (int c = 0; c < 16; ++c) a += wc[c] * ws_ctx[((size_t)b*16 + c)*TWOH + d];
    ws_rnnT[(size_t)d*64 + b] = a * inv;
  }
  const int xb = x[b];
  for (int e = threadIdx.x; e < EMB; e += 256)
    ws_rnnT[(size_t)(TWOH + e)*64 + b] = emb_table[(size_t)xb*EMB + e];
  for (int k = threadIdx.x; k < HDIM; k += 256)
    ws_hidT[(size_t)k*64 + b] = hidden[b*HDIM + k];
}

// K3 v3: gate partials with async-STAGE (reg-prefetch next chunk during compute).
__global__ __launch_bounds__(256) void k_gates(const float* __restrict__ ws_rnnT,
                                               const float* __restrict__ ws_hidT,
                                               const float* __restrict__ W_ih,
                                               const float* __restrict__ W_hh,
                                               float* __restrict__ ws_gp) {
  __shared__ float  lds_h[128*64];   // 32 KB
  __shared__ float4 lds_w[32*32];    // 16 KB
  const int lane = threadIdx.x & 63;
  const int wave = threadIdx.x >> 6;
  const int part = blockIdx.x >> 7;    // 0..3
  const int rg   = blockIdx.x & 127;   // 0..127
  const int j0   = rg * 32;
  const int r0   = wave * 8;
  const int tid  = threadIdx.x;

  float4 ph[8], pw[4];

#define G_LOAD(C)                                                             \
  {                                                                           \
    const int kg = part*896 + (C)*128;                                        \
    const float* hsrc = (kg < KDIM) ? (ws_rnnT + (size_t)kg*64)               \
                                    : (ws_hidT + (size_t)(kg - KDIM)*64);     \
    const float4* s4 = reinterpret_cast<const float4*>(hsrc);                 \
    _Pragma("unroll")                                                         \
    for (int j = 0; j < 8; ++j) ph[j] = s4[tid + 256*j];                      \
    _Pragma("unroll")                                                         \
    for (int j = 0; j < 4; ++j) {                                             \
      const int i = tid + 256*j;                                              \
      const int r = i >> 5, cc = i & 31;                                      \
      const int jrow = j0 + r;                                                \
      const float* wrow = (kg < KDIM) ? (W_ih + (size_t)jrow*KDIM + kg)       \
                                      : (W_hh + (size_t)jrow*HDIM + (kg-KDIM));\
      pw[j] = *reinterpret_cast<const float4*>(wrow + cc*4);                  \
    }                                                                         \
  }

#define G_STORE()                                                             \
  {                                                                           \
    float4* l4 = reinterpret_cast<float4*>(lds_h);                            \
    _Pragma("unroll")                                                         \
    for (int j = 0; j < 8; ++j) l4[tid + 256*j] = ph[j];                      \
    _Pragma("unroll")                                                         \
    for (int j = 0; j < 4; ++j) lds_w[tid + 256*j] = pw[j];                   \
  }

  float acc[8];
#pragma unroll
  for (int r = 0; r < 8; ++r) acc[r] = 0.f;

  G_LOAD(0)
  G_STORE()
  __syncthreads();

  for (int c = 0; c < 7; ++c) {
    if (c < 6) G_LOAD(c+1)
    for (int kk = 0; kk < 128; kk += 4) {
      const float v0 = lds_h[(kk+0)*64 + lane];
      const float v1 = lds_h[(kk+1)*64 + lane];
      const float v2 = lds_h[(kk+2)*64 + lane];
      const float v3 = lds_h[(kk+3)*64 + lane];
      const int wbase = r0*32 + (kk >> 2);
#pragma unroll
      for (int r = 0; r < 8; ++r) {
        const float4 wv = lds_w[wbase + r*32];
        acc[r] = fmaf(v0, wv.x, acc[r]);
        acc[r] = fmaf(v1, wv.y, acc[r]);
        acc[r] = fmaf(v2, wv.z, acc[r]);
        acc[r] = fmaf(v3, wv.w, acc[r]);
      }
    }
    if (c < 6) {
      __syncthreads();
      G_STORE()
      __syncthreads();
    }
  }
#undef G_LOAD
#undef G_STORE

#pragma unroll
  for (int r = 0; r < 8; ++r)
    ws_gp[((size_t)part*4096 + j0 + r0 + r)*64 + lane] = acc[r];
}

// K3b: sum 4 partials + biases, LSTM pointwise.
__global__ __launch_bounds__(256) void k_lstm(const float* __restrict__ ws_gp,
                                              const float* __restrict__ b_ih,
                                              const float* __restrict__ b_hh,
                                              const float* __restrict__ cell,
                                              float* __restrict__ out_h,
                                              float* __restrict__ out_c,
                                              float* __restrict__ ws_hT) {
  const int id = blockIdx.x*256 + threadIdx.x;  // 65536
  const int h = id >> 6, b = id & 63;
  float g[4];
#pragma unroll
  for (int gg = 0; gg < 4; ++gg) {
    const int j = gg*1024 + h;
    float v = b_ih[j] + b_hh[j];
#pragma unroll
    for (int p = 0; p < 4; ++p) v += ws_gp[((size_t)p*4096 + j)*64 + b];
    g[gg] = v;
  }
  const float iv = sigmoidf_(g[0]);
  const float fv = sigmoidf_(g[1]);
  const float gv = tanhf(g[2]);
  const float ov = sigmoidf_(g[3]);
  const float cold = cell[b*HDIM + h];
  const float cn = fmaf(fv, cold, iv*gv);
  const float hn = ov * tanhf(cn);
  out_h[b*HDIM + h] = hn;
  out_c[b*HDIM + h] = cn;
  ws_hT[(size_t)h*64 + b] = hn;
}

// K4 v5: 64 rows/block, 16 rows/wave + async-STAGE reg-prefetch.
__global__ __launch_bounds__(256) void k_fc(const float* __restrict__ ws_hT,
                                            const float* __restrict__ fc_W,
                                            const float* __restrict__ fc_b,
                                            float* __restrict__ preds) {
  __shared__ float  lds_h[128*64];   // 32 KB
  __shared__ float4 lds_w[64*32];    // 32 KB
  const int lane = threadIdx.x & 63;
  const int wave = threadIdx.x >> 6;
  const int ob = blockIdx.x * 64;
  const int r0 = wave * 16;
  const int tid = threadIdx.x;

  float4 ph[8], pw[8];

#define F_LOAD(C)                                                             \
  {                                                                           \
    const int k0 = (C)*128;                                                   \
    const float4* s4 = reinterpret_cast<const float4*>(ws_hT + (size_t)k0*64);\
    _Pragma("unroll")                                                         \
    for (int j = 0; j < 8; ++j) ph[j] = s4[tid + 256*j];                      \
    _Pragma("unroll")                                                         \
    for (int j = 0; j < 8; ++j) {                                             \
      const int i = tid + 256*j;                                              \
      const int r = i >> 5, cc = i & 31;                                      \
      pw[j] = *reinterpret_cast<const float4*>(                               \
                 fc_W + (size_t)(ob + r)*HDIM + k0 + cc*4);                   \
    }                                                                         \
  }

#define F_STORE()                                                             \
  {                                                                           \
    float4* l4 = reinterpret_cast<float4*>(lds_h);                            \
    _Pragma("unroll")                                                         \
    for (int j = 0; j < 8; ++j) l4[tid + 256*j] = ph[j];                      \
    _Pragma("unroll")                                                         \
    for (int j = 0; j < 8; ++j) lds_w[tid + 256*j] = pw[j];                   \
  }

  float acc[16];
#pragma unroll
  for (int r = 0; r < 16; ++r) acc[r] = 0.f;

  F_LOAD(0)
  F_STORE()
  __syncthreads();

  for (int c = 0; c < 8; ++c) {
    if (c < 7) F_LOAD(c+1)
    for (int kk = 0; kk < 128; kk += 4) {
      const float v0 = lds_h[(kk+0)*64 + lane];
      const float v1 = lds_h[(kk+1)*64 + lane];
      const float v2 = lds_h[(kk+2)*64 + lane];
      const float v3 = lds_h[(kk+3)*64 + lane];
      const int wbase = r0*32 + (kk >> 2);
#pragma unroll
      for (int r = 0; r < 16; ++r) {
        const float4 wv = lds_w[wbase + r*32];
        acc[r] = fmaf(v0, wv.x, acc[r]);
        acc[r] = fmaf(v1, wv.y, acc[r]);
        acc[r] = fmaf(v2, wv.z, acc[r]);
        acc[r] = fmaf(v3, wv.w, acc[r]);
      }
    }
    if (c < 7) {
      __syncthreads();
      F_STORE()
      __syncthreads();
    }
  }
#undef F_LOAD
#undef F_STORE

  const int orow = ob + r0;
  float* p = preds + (size_t)lane*VOUT + orow;
#pragma unroll
  for (int r4 = 0; r4 < 16; r4 += 4) {
    float4 st = make_float4(acc[r4]   + fc_b[orow + r4],
                            acc[r4+1] + fc_b[orow + r4+1],
                            acc[r4+2] + fc_b[orow + r4+2],
                            acc[r4+3] + fc_b[orow + r4+3]);
    *reinterpret_cast<float4*>(p + r4) = st;
  }
}

extern "C" void kernel_launch(void* const* d_in, const int* in_sizes, int n_in,
                              void* d_out, int out_size, void* d_ws, size_t ws_size,
                              hipStream_t stream) {
  const int*   x      = (const int*)  d_in[0];
  const float* enc    = (const float*)d_in[1];
  const float* hidden = (const float*)d_in[2];
  const float* cell   = (const float*)d_in[3];
  const float* embt   = (const float*)d_in[4];
  const float* eW     = (const float*)d_in[5];
  const float* eb     = (const float*)d_in[6];
  const float* W_ih   = (const float*)d_in[7];
  const float* W_hh   = (const float*)d_in[8];
  const float* b_ih   = (const float*)d_in[9];
  const float* b_hh   = (const float*)d_in[10];
  const float* fc_W   = (const float*)d_in[11];
  const float* fc_b   = (const float*)d_in[12];

  float* out   = (float*)d_out;
  float* preds = out;                              // 64*32000
  float* out_h = out + (size_t)BATCH*VOUT;         // 64*1024
  float* out_c = out_h + BATCH*HDIM;               // 64*1024
  float* ws    = (float*)d_ws;

  k_attn<<<dim3(16, 64), 256, 0, stream>>>(enc, eW, eb, hidden, ws + WS_MS, ws + WS_CTX);
  k_combine<<<64, 256, 0, stream>>>(ws + WS_MS, ws + WS_CTX, hidden, embt, x,
                                    ws + WS_RNNT, ws + WS_HIDT);
  k_gates<<<512, 256, 0, stream>>>(ws + WS_RNNT, ws + WS_HIDT, W_ih, W_hh, ws + WS_GP);
  k_lstm<<<256, 256, 0, stream>>>(ws + WS_GP, b_ih, b_hh, cell, out_h, out_c, ws + WS_HT);
  k_fc<<<500, 256, 0, stream>>>(ws + WS_HT, fc_W, fc_b, preds);
}

// Round 9
// 204.851 us; speedup vs baseline: 1.5554x; 1.5554x over previous
//
#include <hip/hip_runtime.h>

#define S_LEN 512
#define BATCH 64
#define HDIM  1024
#define TWOH  2048
#define EMB   512
#define KDIM  2560      // 2H + EMB
#define VOUT  32000

// ws layout (float offsets)
#define WS_MS    64
#define WS_CTX   2112
#define WS_GP    WS_CTX                      // gate partials [4][4096][64] alias dead ctx region
#define WS_RNNT  (WS_CTX + 64*16*2048)       // 2,099,264
#define WS_HIDT  (WS_RNNT + KDIM*64)         // 2,263,104
#define WS_HT    (WS_HIDT + HDIM*64)         // 2,328,640

typedef __attribute__((ext_vector_type(8))) short bf16x8;
typedef __attribute__((ext_vector_type(4))) float f32x4;

__device__ __forceinline__ float sigmoidf_(float x) { return 1.f/(1.f+__expf(-x)); }

// RNE float -> bf16 (finite inputs)
__device__ __forceinline__ short f2bf(float f) {
  union { float f; unsigned u; } v; v.f = f;
  return (short)((v.u + 0x7fffu + ((v.u >> 16) & 1u)) >> 16);
}

// K1 v3: single-pass online-softmax context, row-pipelined, hb inline.
__global__ __launch_bounds__(256) void k_attn(const float* __restrict__ enc,
                                              const float* __restrict__ eW,
                                              const float* __restrict__ eb,
                                              const float* __restrict__ hidden,
                                              float* __restrict__ ws_ms,
                                              float* __restrict__ ws_ctx) {
  __shared__ float lds_ms[4][2];
  __shared__ float lds_ctx[4][2048];
  const int lane  = threadIdx.x & 63;
  const int wave  = threadIdx.x >> 6;
  const int chunk = blockIdx.x;   // 0..15
  const int b     = blockIdx.y;   // 0..63

  float hba = 0.f;
  for (int k = lane; k < HDIM; k += 64) hba += hidden[b*HDIM + k] * eW[k];
#pragma unroll
  for (int st = 32; st >= 1; st >>= 1) hba += __shfl_xor(hba, st, 64);
  const float hb = hba + eb[0];

  float4 w4[8];
#pragma unroll
  for (int k = 0; k < 8; ++k)
    w4[k] = *reinterpret_cast<const float4*>(eW + HDIM + 4*lane + 256*k);

  const int s0 = chunk*32 + wave*8;
  const float* base = enc + ((size_t)(s0*BATCH + b))*TWOH + 4*lane;

  float m = 0.f, ssum = 0.f;      // relu => e >= 0
  float4 ctx[8];
#pragma unroll
  for (int k = 0; k < 8; ++k) ctx[k] = make_float4(0.f, 0.f, 0.f, 0.f);

  float4 va[8], vb[8];
#pragma unroll
  for (int k = 0; k < 8; ++k) va[k] = *reinterpret_cast<const float4*>(base + 256*k);

#define ATTN_STEP(VCUR, VNXT, I)                                              \
  {                                                                           \
    if ((I) < 7) {                                                            \
      const float* pn = base + (size_t)((I)+1)*BATCH*TWOH;                    \
      _Pragma("unroll")                                                       \
      for (int k = 0; k < 8; ++k)                                             \
        VNXT[k] = *reinterpret_cast<const float4*>(pn + 256*k);               \
    }                                                                         \
    float a = 0.f;                                                            \
    _Pragma("unroll")                                                         \
    for (int k = 0; k < 8; ++k)                                               \
      a += VCUR[k].x*w4[k].x + VCUR[k].y*w4[k].y +                            \
           VCUR[k].z*w4[k].z + VCUR[k].w*w4[k].w;                             \
    _Pragma("unroll")                                                         \
    for (int st = 1; st < 64; st <<= 1) a += __shfl_xor(a, st, 64);           \
    const float e = fmaxf(a + hb, 0.f);                                       \
    if (e > m) {                                                              \
      const float sc = __expf(m - e);                                         \
      ssum = ssum*sc + 1.f;                                                   \
      _Pragma("unroll")                                                       \
      for (int k = 0; k < 8; ++k) {                                           \
        ctx[k].x = fmaf(ctx[k].x, sc, VCUR[k].x);                             \
        ctx[k].y = fmaf(ctx[k].y, sc, VCUR[k].y);                             \
        ctx[k].z = fmaf(ctx[k].z, sc, VCUR[k].z);                             \
        ctx[k].w = fmaf(ctx[k].w, sc, VCUR[k].w);                             \
      }                                                                       \
      m = e;                                                                  \
    } else {                                                                  \
      const float pw = __expf(e - m);                                         \
      ssum += pw;                                                             \
      _Pragma("unroll")                                                       \
      for (int k = 0; k < 8; ++k) {                                           \
        ctx[k].x = fmaf(pw, VCUR[k].x, ctx[k].x);                             \
        ctx[k].y = fmaf(pw, VCUR[k].y, ctx[k].y);                             \
        ctx[k].z = fmaf(pw, VCUR[k].z, ctx[k].z);                             \
        ctx[k].w = fmaf(pw, VCUR[k].w, ctx[k].w);                             \
      }                                                                       \
    }                                                                         \
  }

  ATTN_STEP(va, vb, 0)
  ATTN_STEP(vb, va, 1)
  ATTN_STEP(va, vb, 2)
  ATTN_STEP(vb, va, 3)
  ATTN_STEP(va, vb, 4)
  ATTN_STEP(vb, va, 5)
  ATTN_STEP(va, vb, 6)
  ATTN_STEP(vb, va, 7)
#undef ATTN_STEP

  if (lane == 0) { lds_ms[wave][0] = m; lds_ms[wave][1] = ssum; }
  __syncthreads();
  const float M = fmaxf(fmaxf(lds_ms[0][0], lds_ms[1][0]),
                        fmaxf(lds_ms[2][0], lds_ms[3][0]));
  const float wsc = __expf(m - M);
  float ssum_c = 0.f;
#pragma unroll
  for (int w = 0; w < 4; ++w) ssum_c += __expf(lds_ms[w][0] - M) * lds_ms[w][1];
#pragma unroll
  for (int k = 0; k < 8; ++k) {
    float4 c = ctx[k];
    c.x *= wsc; c.y *= wsc; c.z *= wsc; c.w *= wsc;
    *reinterpret_cast<float4*>(&lds_ctx[wave][4*lane + 256*k]) = c;
  }
  __syncthreads();
  float* outp = ws_ctx + ((size_t)b*16 + chunk)*TWOH;
  for (int d = threadIdx.x; d < TWOH; d += 256)
    outp[d] = lds_ctx[0][d] + lds_ctx[1][d] + lds_ctx[2][d] + lds_ctx[3][d];
  if (threadIdx.x == 0) {
    ws_ms[((size_t)b*16 + chunk)*2]     = M;
    ws_ms[((size_t)b*16 + chunk)*2 + 1] = ssum_c;
  }
}

// K2: combine 16 chunk-partials per b; build transposed rnn input + hidden.
__global__ __launch_bounds__(256) void k_combine(const float* __restrict__ ws_ms,
                                                 const float* __restrict__ ws_ctx,
                                                 const float* __restrict__ hidden,
                                                 const float* __restrict__ emb_table,
                                                 const int* __restrict__ x,
                                                 float* __restrict__ ws_rnnT,
                                                 float* __restrict__ ws_hidT) {
  const int b = blockIdx.x;
  float mc[16], sc[16];
#pragma unroll
  for (int c = 0; c < 16; ++c) {
    mc[c] = ws_ms[(b*16 + c)*2];
    sc[c] = ws_ms[(b*16 + c)*2 + 1];
  }
  float M = mc[0];
#pragma unroll
  for (int c = 1; c < 16; ++c) M = fmaxf(M, mc[c]);
  float wc[16], Ssum = 0.f;
#pragma unroll
  for (int c = 0; c < 16; ++c) { wc[c] = __expf(mc[c] - M); Ssum += wc[c]*sc[c]; }
  const float inv = 1.f / Ssum;
  for (int d = threadIdx.x; d < TWOH; d += 256) {
    float a = 0.f;
#pragma unroll
    for (int c = 0; c < 16; ++c) a += wc[c] * ws_ctx[((size_t)b*16 + c)*TWOH + d];
    ws_rnnT[(size_t)d*64 + b] = a * inv;
  }
  const int xb = x[b];
  for (int e = threadIdx.x; e < EMB; e += 256)
    ws_rnnT[(size_t)(TWOH + e)*64 + b] = emb_table[(size_t)xb*EMB + e];
  for (int k = threadIdx.x; k < HDIM; k += 256)
    ws_hidT[(size_t)k*64 + b] = hidden[b*HDIM + k];
}

// K3 (round-7 version, no prefetch): gate partials. Split-K=4.
__global__ __launch_bounds__(256) void k_gates(const float* __restrict__ ws_rnnT,
                                               const float* __restrict__ ws_hidT,
                                               const float* __restrict__ W_ih,
                                               const float* __restrict__ W_hh,
                                               float* __restrict__ ws_gp) {
  __shared__ float  lds_h[128*64];   // 32 KB
  __shared__ float4 lds_w[32*32];    // 16 KB
  const int lane = threadIdx.x & 63;
  const int wave = threadIdx.x >> 6;
  const int part = blockIdx.x >> 7;    // 0..3
  const int rg   = blockIdx.x & 127;   // 0..127
  const int j0   = rg * 32;
  const int r0   = wave * 8;

  float acc[8];
#pragma unroll
  for (int r = 0; r < 8; ++r) acc[r] = 0.f;

  for (int c = 0; c < 7; ++c) {
    const int kg = part*896 + c*128;
    const float* hsrc = (kg < KDIM) ? (ws_rnnT + (size_t)kg*64)
                                    : (ws_hidT + (size_t)(kg - KDIM)*64);
    const float4* s4 = reinterpret_cast<const float4*>(hsrc);
    float4* l4 = reinterpret_cast<float4*>(lds_h);
    for (int i = threadIdx.x; i < 2048; i += 256) l4[i] = s4[i];
    for (int i = threadIdx.x; i < 1024; i += 256) {
      const int r = i >> 5, cc = i & 31;
      const int j = j0 + r;
      const float* wrow = (kg < KDIM) ? (W_ih + (size_t)j*KDIM + kg)
                                      : (W_hh + (size_t)j*HDIM + (kg - KDIM));
      lds_w[i] = *reinterpret_cast<const float4*>(wrow + cc*4);
    }
    __syncthreads();
    for (int kk = 0; kk < 128; kk += 4) {
      const float v0 = lds_h[(kk+0)*64 + lane];
      const float v1 = lds_h[(kk+1)*64 + lane];
      const float v2 = lds_h[(kk+2)*64 + lane];
      const float v3 = lds_h[(kk+3)*64 + lane];
      const int wbase = r0*32 + (kk >> 2);
#pragma unroll
      for (int r = 0; r < 8; ++r) {
        const float4 wv = lds_w[wbase + r*32];
        acc[r] = fmaf(v0, wv.x, acc[r]);
        acc[r] = fmaf(v1, wv.y, acc[r]);
        acc[r] = fmaf(v2, wv.z, acc[r]);
        acc[r] = fmaf(v3, wv.w, acc[r]);
      }
    }
    __syncthreads();
  }
#pragma unroll
  for (int r = 0; r < 8; ++r)
    ws_gp[((size_t)part*4096 + j0 + r0 + r)*64 + lane] = acc[r];
}

// K3b: sum 4 partials + biases, LSTM pointwise.
__global__ __launch_bounds__(256) void k_lstm(const float* __restrict__ ws_gp,
                                              const float* __restrict__ b_ih,
                                              const float* __restrict__ b_hh,
                                              const float* __restrict__ cell,
                                              float* __restrict__ out_h,
                                              float* __restrict__ out_c,
                                              float* __restrict__ ws_hT) {
  const int id = blockIdx.x*256 + threadIdx.x;  // 65536
  const int h = id >> 6, b = id & 63;
  float g[4];
#pragma unroll
  for (int gg = 0; gg < 4; ++gg) {
    const int j = gg*1024 + h;
    float v = b_ih[j] + b_hh[j];
#pragma unroll
    for (int p = 0; p < 4; ++p) v += ws_gp[((size_t)p*4096 + j)*64 + b];
    g[gg] = v;
  }
  const float iv = sigmoidf_(g[0]);
  const float fv = sigmoidf_(g[1]);
  const float gv = tanhf(g[2]);
  const float ov = sigmoidf_(g[3]);
  const float cold = cell[b*HDIM + h];
  const float cn = fmaf(fv, cold, iv*gv);
  const float hn = ov * tanhf(cn);
  out_h[b*HDIM + h] = hn;
  out_c[b*HDIM + h] = cn;
  ws_hT[(size_t)h*64 + b] = hn;
}

// K4 v6: MFMA bf16 GEMM. preds[64, 32000] = h[64,1024] . fc_W^T + fc_b.
// Wave = 16 W-rows x 64 batch (4 n-tiles of 16x16x32). No LDS, no barriers.
// A = fc_W rows (m=lane&15, k=(lane>>4)*8+i), B = ws_hT [k][b] (n=lane&15).
// W streams HBM once (131 MB); h (256 KB) is L2-hot.
__global__ __launch_bounds__(256) void k_fc(const float* __restrict__ ws_hT,
                                            const float* __restrict__ fc_W,
                                            const float* __restrict__ fc_b,
                                            float* __restrict__ preds) {
  const int lane = threadIdx.x & 63;
  const int wave = threadIdx.x >> 6;
  const int row0 = (blockIdx.x*4 + wave)*16;   // grid 500 -> 32000 rows
  const int mlo  = lane & 15;                  // A-row / B-col local idx
  const int kg   = lane >> 4;                  // 0..3 k-group

  const float* wrow = fc_W + (size_t)(row0 + mlo)*HDIM + kg*8;

  f32x4 acc0 = {0.f,0.f,0.f,0.f}, acc1 = acc0, acc2 = acc0, acc3 = acc0;

  for (int k0 = 0; k0 < HDIM; k0 += 32) {
    const float4 wa = *reinterpret_cast<const float4*>(wrow + k0);
    const float4 wb = *reinterpret_cast<const float4*>(wrow + k0 + 4);
    bf16x8 afrag;
    afrag[0] = f2bf(wa.x); afrag[1] = f2bf(wa.y);
    afrag[2] = f2bf(wa.z); afrag[3] = f2bf(wa.w);
    afrag[4] = f2bf(wb.x); afrag[5] = f2bf(wb.y);
    afrag[6] = f2bf(wb.z); afrag[7] = f2bf(wb.w);

    const float* hp = ws_hT + (size_t)(k0 + kg*8)*64 + mlo;
    bf16x8 b0, b1, b2, b3;
#pragma unroll
    for (int i = 0; i < 8; ++i) {
      b0[i] = f2bf(hp[i*64]);
      b1[i] = f2bf(hp[i*64 + 16]);
      b2[i] = f2bf(hp[i*64 + 32]);
      b3[i] = f2bf(hp[i*64 + 48]);
    }
    acc0 = __builtin_amdgcn_mfma_f32_16x16x32_bf16(afrag, b0, acc0, 0, 0, 0);
    acc1 = __builtin_amdgcn_mfma_f32_16x16x32_bf16(afrag, b1, acc1, 0, 0, 0);
    acc2 = __builtin_amdgcn_mfma_f32_16x16x32_bf16(afrag, b2, acc2, 0, 0, 0);
    acc3 = __builtin_amdgcn_mfma_f32_16x16x32_bf16(afrag, b3, acc3, 0, 0, 0);
  }

  // C/D layout: col = lane&15 (batch), row = (lane>>4)*4 + j (W-row)
  const int mbase = row0 + kg*4;
  const float4 bias = make_float4(fc_b[mbase], fc_b[mbase+1],
                                  fc_b[mbase+2], fc_b[mbase+3]);
#define FC_STORE(ACC, N)                                                      \
  {                                                                           \
    float4 st = make_float4(ACC[0] + bias.x, ACC[1] + bias.y,                 \
                            ACC[2] + bias.z, ACC[3] + bias.w);                \
    *reinterpret_cast<float4*>(preds + (size_t)((N)*16 + mlo)*VOUT + mbase) = st; \
  }
  FC_STORE(acc0, 0) FC_STORE(acc1, 1) FC_STORE(acc2, 2) FC_STORE(acc3, 3)
#undef FC_STORE
}

extern "C" void kernel_launch(void* const* d_in, const int* in_sizes, int n_in,
                              void* d_out, int out_size, void* d_ws, size_t ws_size,
                              hipStream_t stream) {
  const int*   x      = (const int*)  d_in[0];
  const float* enc    = (const float*)d_in[1];
  const float* hidden = (const float*)d_in[2];
  const float* cell   = (const float*)d_in[3];
  const float* embt   = (const float*)d_in[4];
  const float* eW     = (const float*)d_in[5];
  const float* eb     = (const float*)d_in[6];
  const float* W_ih   = (const float*)d_in[7];
  const float* W_hh   = (const float*)d_in[8];
  const float* b_ih   = (const float*)d_in[9];
  const float* b_hh   = (const float*)d_in[10];
  const float* fc_W   = (const float*)d_in[11];
  const float* fc_b   = (const float*)d_in[12];

  float* out   = (float*)d_out;
  float* preds = out;                              // 64*32000
  float* out_h = out + (size_t)BATCH*VOUT;         // 64*1024
  float* out_c = out_h + BATCH*HDIM;               // 64*1024
  float* ws    = (float*)d_ws;

  k_attn<<<dim3(16, 64), 256, 0, stream>>>(enc, eW, eb, hidden, ws + WS_MS, ws + WS_CTX);
  k_combine<<<64, 256, 0, stream>>>(ws + WS_MS, ws + WS_CTX, hidden, embt, x,
                                    ws + WS_RNNT, ws + WS_HIDT);
  k_gates<<<512, 256, 0, stream>>>(ws + WS_RNNT, ws + WS_HIDT, W_ih, W_hh, ws + WS_GP);
  k_lstm<<<256, 256, 0, stream>>>(ws + WS_GP, b_ih, b_hh, cell, out_h, out_c, ws + WS_HT);
  k_fc<<<500, 256, 0, stream>>>(ws + WS_HT, fc_W, fc_b, preds);
}

// Round 10
// 150.516 us; speedup vs baseline: 2.1170x; 1.3610x over previous
//
#include <hip/hip_runtime.h>

#define S_LEN 512
#define BATCH 64
#define HDIM  1024
#define TWOH  2048
#define EMB   512
#define KDIM  2560      // 2H + EMB
#define KTOT  3584      // 2H + EMB + H
#define VOUT  32000

// ws layout (float offsets)
#define WS_MS    64
#define WS_CTX   2112                        // f32 [64][16][2048] = 2,097,152 floats
#define WS_GP    WS_CTX                      // gate partials [8][4096][64] f32 — aliases dead ctx
#define WS_RNNB  (WS_CTX + 64*16*2048)       // bf16 [64][3584] = 114,688 floats
#define WS_HB16  (WS_RNNB + 114688)          // bf16 [64][1024] = 32,768 floats

typedef __attribute__((ext_vector_type(8))) short bf16x8;
typedef __attribute__((ext_vector_type(4))) float f32x4;

__device__ __forceinline__ float sigmoidf_(float x) { return 1.f/(1.f+__expf(-x)); }

// RNE float -> bf16 (finite inputs)
__device__ __forceinline__ unsigned short f2bf(float f) {
  union { float f; unsigned u; } v; v.f = f;
  return (unsigned short)((v.u + 0x7fffu + ((v.u >> 16) & 1u)) >> 16);
}

// K1 v3: single-pass online-softmax context, row-pipelined, hb inline.
__global__ __launch_bounds__(256) void k_attn(const float* __restrict__ enc,
                                              const float* __restrict__ eW,
                                              const float* __restrict__ eb,
                                              const float* __restrict__ hidden,
                                              float* __restrict__ ws_ms,
                                              float* __restrict__ ws_ctx) {
  __shared__ float lds_ms[4][2];
  __shared__ float lds_ctx[4][2048];
  const int lane  = threadIdx.x & 63;
  const int wave  = threadIdx.x >> 6;
  const int chunk = blockIdx.x;   // 0..15
  const int b     = blockIdx.y;   // 0..63

  float hba = 0.f;
  for (int k = lane; k < HDIM; k += 64) hba += hidden[b*HDIM + k] * eW[k];
#pragma unroll
  for (int st = 32; st >= 1; st >>= 1) hba += __shfl_xor(hba, st, 64);
  const float hb = hba + eb[0];

  float4 w4[8];
#pragma unroll
  for (int k = 0; k < 8; ++k)
    w4[k] = *reinterpret_cast<const float4*>(eW + HDIM + 4*lane + 256*k);

  const int s0 = chunk*32 + wave*8;
  const float* base = enc + ((size_t)(s0*BATCH + b))*TWOH + 4*lane;

  float m = 0.f, ssum = 0.f;      // relu => e >= 0
  float4 ctx[8];
#pragma unroll
  for (int k = 0; k < 8; ++k) ctx[k] = make_float4(0.f, 0.f, 0.f, 0.f);

  float4 va[8], vb[8];
#pragma unroll
  for (int k = 0; k < 8; ++k) va[k] = *reinterpret_cast<const float4*>(base + 256*k);

#define ATTN_STEP(VCUR, VNXT, I)                                              \
  {                                                                           \
    if ((I) < 7) {                                                            \
      const float* pn = base + (size_t)((I)+1)*BATCH*TWOH;                    \
      _Pragma("unroll")                                                       \
      for (int k = 0; k < 8; ++k)                                             \
        VNXT[k] = *reinterpret_cast<const float4*>(pn + 256*k);               \
    }                                                                         \
    float a = 0.f;                                                            \
    _Pragma("unroll")                                                         \
    for (int k = 0; k < 8; ++k)                                               \
      a += VCUR[k].x*w4[k].x + VCUR[k].y*w4[k].y +                            \
           VCUR[k].z*w4[k].z + VCUR[k].w*w4[k].w;                             \
    _Pragma("unroll")                                                         \
    for (int st = 1; st < 64; st <<= 1) a += __shfl_xor(a, st, 64);           \
    const float e = fmaxf(a + hb, 0.f);                                       \
    if (e > m) {                                                              \
      const float sc = __expf(m - e);                                         \
      ssum = ssum*sc + 1.f;                                                   \
      _Pragma("unroll")                                                       \
      for (int k = 0; k < 8; ++k) {                                           \
        ctx[k].x = fmaf(ctx[k].x, sc, VCUR[k].x);                             \
        ctx[k].y = fmaf(ctx[k].y, sc, VCUR[k].y);                             \
        ctx[k].z = fmaf(ctx[k].z, sc, VCUR[k].z);                             \
        ctx[k].w = fmaf(ctx[k].w, sc, VCUR[k].w);                             \
      }                                                                       \
      m = e;                                                                  \
    } else {                                                                  \
      const float pw = __expf(e - m);                                         \
      ssum += pw;                                                             \
      _Pragma("unroll")                                                       \
      for (int k = 0; k < 8; ++k) {                                           \
        ctx[k].x = fmaf(pw, VCUR[k].x, ctx[k].x);                             \
        ctx[k].y = fmaf(pw, VCUR[k].y, ctx[k].y);                             \
        ctx[k].z = fmaf(pw, VCUR[k].z, ctx[k].z);                             \
        ctx[k].w = fmaf(pw, VCUR[k].w, ctx[k].w);                             \
      }                                                                       \
    }                                                                         \
  }

  ATTN_STEP(va, vb, 0)
  ATTN_STEP(vb, va, 1)
  ATTN_STEP(va, vb, 2)
  ATTN_STEP(vb, va, 3)
  ATTN_STEP(va, vb, 4)
  ATTN_STEP(vb, va, 5)
  ATTN_STEP(va, vb, 6)
  ATTN_STEP(vb, va, 7)
#undef ATTN_STEP

  if (lane == 0) { lds_ms[wave][0] = m; lds_ms[wave][1] = ssum; }
  __syncthreads();
  const float M = fmaxf(fmaxf(lds_ms[0][0], lds_ms[1][0]),
                        fmaxf(lds_ms[2][0], lds_ms[3][0]));
  const float wsc = __expf(m - M);
  float ssum_c = 0.f;
#pragma unroll
  for (int w = 0; w < 4; ++w) ssum_c += __expf(lds_ms[w][0] - M) * lds_ms[w][1];
#pragma unroll
  for (int k = 0; k < 8; ++k) {
    float4 c = ctx[k];
    c.x *= wsc; c.y *= wsc; c.z *= wsc; c.w *= wsc;
    *reinterpret_cast<float4*>(&lds_ctx[wave][4*lane + 256*k]) = c;
  }
  __syncthreads();
  float* outp = ws_ctx + ((size_t)b*16 + chunk)*TWOH;
  for (int d = threadIdx.x; d < TWOH; d += 256)
    outp[d] = lds_ctx[0][d] + lds_ctx[1][d] + lds_ctx[2][d] + lds_ctx[3][d];
  if (threadIdx.x == 0) {
    ws_ms[((size_t)b*16 + chunk)*2]     = M;
    ws_ms[((size_t)b*16 + chunk)*2 + 1] = ssum_c;
  }
}

// K2 v3: combine 16 chunk-partials; emit bf16 rnnB [b][KTOT] = ctx | emb | hidden.
__global__ __launch_bounds__(256) void k_combine(const float* __restrict__ ws_ms,
                                                 const float* __restrict__ ws_ctx,
                                                 const float* __restrict__ hidden,
                                                 const float* __restrict__ emb_table,
                                                 const int* __restrict__ x,
                                                 unsigned short* __restrict__ rnnB) {
  const int b = blockIdx.x;
  float mc[16], sc[16];
#pragma unroll
  for (int c = 0; c < 16; ++c) {
    mc[c] = ws_ms[(b*16 + c)*2];
    sc[c] = ws_ms[(b*16 + c)*2 + 1];
  }
  float M = mc[0];
#pragma unroll
  for (int c = 1; c < 16; ++c) M = fmaxf(M, mc[c]);
  float wc[16], Ssum = 0.f;
#pragma unroll
  for (int c = 0; c < 16; ++c) { wc[c] = __expf(mc[c] - M); Ssum += wc[c]*sc[c]; }
  const float inv = 1.f / Ssum;
  unsigned short* rb = rnnB + (size_t)b*KTOT;
  for (int d = threadIdx.x; d < TWOH; d += 256) {
    float a = 0.f;
#pragma unroll
    for (int c = 0; c < 16; ++c) a += wc[c] * ws_ctx[((size_t)b*16 + c)*TWOH + d];
    rb[d] = f2bf(a * inv);
  }
  const int xb = x[b];
  for (int e = threadIdx.x; e < EMB; e += 256)
    rb[TWOH + e] = f2bf(emb_table[(size_t)xb*EMB + e]);
  for (int k = threadIdx.x; k < HDIM; k += 256)
    rb[KDIM + k] = f2bf(hidden[b*HDIM + k]);
}

// K3 v4: MFMA gate GEMM. gates[4096,64] = [W_ih | W_hh] x rnnB^T, split-K=8.
// Wave = 16 gate-rows x 64 batch (4 n-tiles 16x16x32). grid 512 = 64 rg x 8 part.
__global__ __launch_bounds__(256) void k_gates(const unsigned short* __restrict__ rnnB,
                                               const float* __restrict__ W_ih,
                                               const float* __restrict__ W_hh,
                                               float* __restrict__ ws_gp) {
  const int lane = threadIdx.x & 63;
  const int wave = threadIdx.x >> 6;
  const int part = blockIdx.x & 7;     // k-part: 448 each
  const int rg   = blockIdx.x >> 3;    // 0..63
  const int row0 = rg*64 + wave*16;
  const int mlo  = lane & 15;
  const int kg   = lane >> 4;
  const int j    = row0 + mlo;

  f32x4 acc0 = {0.f,0.f,0.f,0.f}, acc1 = acc0, acc2 = acc0, acc3 = acc0;

  for (int k0 = 0; k0 < 448; k0 += 32) {
    const int kbase = part*448 + k0;           // 32-chunk never crosses KDIM (both %32==0)
    const float* wsrc = (kbase < KDIM)
        ? (W_ih + (size_t)j*KDIM + kbase + kg*8)
        : (W_hh + (size_t)j*HDIM + (kbase - KDIM) + kg*8);
    const float4 wa = *reinterpret_cast<const float4*>(wsrc);
    const float4 wb = *reinterpret_cast<const float4*>(wsrc + 4);
    bf16x8 afrag;
    afrag[0] = f2bf(wa.x); afrag[1] = f2bf(wa.y);
    afrag[2] = f2bf(wa.z); afrag[3] = f2bf(wa.w);
    afrag[4] = f2bf(wb.x); afrag[5] = f2bf(wb.y);
    afrag[6] = f2bf(wb.z); afrag[7] = f2bf(wb.w);

    const size_t ko = kbase + kg*8;
    const bf16x8 b0 = *reinterpret_cast<const bf16x8*>(rnnB + (size_t)(mlo     )*KTOT + ko);
    const bf16x8 b1 = *reinterpret_cast<const bf16x8*>(rnnB + (size_t)(mlo + 16)*KTOT + ko);
    const bf16x8 b2 = *reinterpret_cast<const bf16x8*>(rnnB + (size_t)(mlo + 32)*KTOT + ko);
    const bf16x8 b3 = *reinterpret_cast<const bf16x8*>(rnnB + (size_t)(mlo + 48)*KTOT + ko);

    acc0 = __builtin_amdgcn_mfma_f32_16x16x32_bf16(afrag, b0, acc0, 0, 0, 0);
    acc1 = __builtin_amdgcn_mfma_f32_16x16x32_bf16(afrag, b1, acc1, 0, 0, 0);
    acc2 = __builtin_amdgcn_mfma_f32_16x16x32_bf16(afrag, b2, acc2, 0, 0, 0);
    acc3 = __builtin_amdgcn_mfma_f32_16x16x32_bf16(afrag, b3, acc3, 0, 0, 0);
  }

  // C: row = row0 + kg*4 + jj (gate row), col = n*16 + mlo (batch)
  const int mbase = row0 + kg*4;
#define G_ST(ACC, N)                                                          \
  {                                                                           \
    _Pragma("unroll")                                                         \
    for (int jj = 0; jj < 4; ++jj)                                            \
      ws_gp[((size_t)part*4096 + mbase + jj)*64 + ((N)*16 + mlo)] = ACC[jj];  \
  }
  G_ST(acc0, 0) G_ST(acc1, 1) G_ST(acc2, 2) G_ST(acc3, 3)
#undef G_ST
}

// K3b: sum 8 partials + biases, LSTM pointwise; emit h as f32 outs + bf16 hB.
__global__ __launch_bounds__(256) void k_lstm(const float* __restrict__ ws_gp,
                                              const float* __restrict__ b_ih,
                                              const float* __restrict__ b_hh,
                                              const float* __restrict__ cell,
                                              float* __restrict__ out_h,
                                              float* __restrict__ out_c,
                                              unsigned short* __restrict__ hB) {
  const int id = blockIdx.x*256 + threadIdx.x;  // 65536
  const int h = id >> 6, b = id & 63;
  float g[4];
#pragma unroll
  for (int gg = 0; gg < 4; ++gg) {
    const int j = gg*1024 + h;
    float v = b_ih[j] + b_hh[j];
#pragma unroll
    for (int p = 0; p < 8; ++p) v += ws_gp[((size_t)p*4096 + j)*64 + b];
    g[gg] = v;
  }
  const float iv = sigmoidf_(g[0]);
  const float fv = sigmoidf_(g[1]);
  const float gv = tanhf(g[2]);
  const float ov = sigmoidf_(g[3]);
  const float cold = cell[b*HDIM + h];
  const float cn = fmaf(fv, cold, iv*gv);
  const float hn = ov * tanhf(cn);
  out_h[b*HDIM + h] = hn;
  out_c[b*HDIM + h] = cn;
  hB[(size_t)b*HDIM + h] = f2bf(hn);
}

// K4 v7: MFMA fc GEMM, B from pre-converted bf16 hB [b][k] (16B frag loads).
__global__ __launch_bounds__(256) void k_fc(const unsigned short* __restrict__ hB,
                                            const float* __restrict__ fc_W,
                                            const float* __restrict__ fc_b,
                                            float* __restrict__ preds) {
  const int lane = threadIdx.x & 63;
  const int wave = threadIdx.x >> 6;
  const int row0 = (blockIdx.x*4 + wave)*16;   // grid 500 -> 32000 rows
  const int mlo  = lane & 15;
  const int kg   = lane >> 4;

  const float* wrow = fc_W + (size_t)(row0 + mlo)*HDIM + kg*8;

  f32x4 acc0 = {0.f,0.f,0.f,0.f}, acc1 = acc0, acc2 = acc0, acc3 = acc0;

  for (int k0 = 0; k0 < HDIM; k0 += 32) {
    const float4 wa = *reinterpret_cast<const float4*>(wrow + k0);
    const float4 wb = *reinterpret_cast<const float4*>(wrow + k0 + 4);
    bf16x8 afrag;
    afrag[0] = f2bf(wa.x); afrag[1] = f2bf(wa.y);
    afrag[2] = f2bf(wa.z); afrag[3] = f2bf(wa.w);
    afrag[4] = f2bf(wb.x); afrag[5] = f2bf(wb.y);
    afrag[6] = f2bf(wb.z); afrag[7] = f2bf(wb.w);

    const size_t ko = k0 + kg*8;
    const bf16x8 b0 = *reinterpret_cast<const bf16x8*>(hB + (size_t)(mlo     )*HDIM + ko);
    const bf16x8 b1 = *reinterpret_cast<const bf16x8*>(hB + (size_t)(mlo + 16)*HDIM + ko);
    const bf16x8 b2 = *reinterpret_cast<const bf16x8*>(hB + (size_t)(mlo + 32)*HDIM + ko);
    const bf16x8 b3 = *reinterpret_cast<const bf16x8*>(hB + (size_t)(mlo + 48)*HDIM + ko);

    acc0 = __builtin_amdgcn_mfma_f32_16x16x32_bf16(afrag, b0, acc0, 0, 0, 0);
    acc1 = __builtin_amdgcn_mfma_f32_16x16x32_bf16(afrag, b1, acc1, 0, 0, 0);
    acc2 = __builtin_amdgcn_mfma_f32_16x16x32_bf16(afrag, b2, acc2, 0, 0, 0);
    acc3 = __builtin_amdgcn_mfma_f32_16x16x32_bf16(afrag, b3, acc3, 0, 0, 0);
  }

  const int mbase = row0 + kg*4;
  const float4 bias = make_float4(fc_b[mbase], fc_b[mbase+1],
                                  fc_b[mbase+2], fc_b[mbase+3]);
#define FC_STORE(ACC, N)                                                      \
  {                                                                           \
    float4 st = make_float4(ACC[0] + bias.x, ACC[1] + bias.y,                 \
                            ACC[2] + bias.z, ACC[3] + bias.w);                \
    *reinterpret_cast<float4*>(preds + (size_t)((N)*16 + mlo)*VOUT + mbase) = st; \
  }
  FC_STORE(acc0, 0) FC_STORE(acc1, 1) FC_STORE(acc2, 2) FC_STORE(acc3, 3)
#undef FC_STORE
}

extern "C" void kernel_launch(void* const* d_in, const int* in_sizes, int n_in,
                              void* d_out, int out_size, void* d_ws, size_t ws_size,
                              hipStream_t stream) {
  const int*   x      = (const int*)  d_in[0];
  const float* enc    = (const float*)d_in[1];
  const float* hidden = (const float*)d_in[2];
  const float* cell   = (const float*)d_in[3];
  const float* embt   = (const float*)d_in[4];
  const float* eW     = (const float*)d_in[5];
  const float* eb     = (const float*)d_in[6];
  const float* W_ih   = (const float*)d_in[7];
  const float* W_hh   = (const float*)d_in[8];
  const float* b_ih   = (const float*)d_in[9];
  const float* b_hh   = (const float*)d_in[10];
  const float* fc_W   = (const float*)d_in[11];
  const float* fc_b   = (const float*)d_in[12];

  float* out   = (float*)d_out;
  float* preds = out;                              // 64*32000
  float* out_h = out + (size_t)BATCH*VOUT;         // 64*1024
  float* out_c = out_h + BATCH*HDIM;               // 64*1024
  float* ws    = (float*)d_ws;
  unsigned short* rnnB = (unsigned short*)(ws + WS_RNNB);
  unsigned short* hB   = (unsigned short*)(ws + WS_HB16);

  k_attn<<<dim3(16, 64), 256, 0, stream>>>(enc, eW, eb, hidden, ws + WS_MS, ws + WS_CTX);
  k_combine<<<64, 256, 0, stream>>>(ws + WS_MS, ws + WS_CTX, hidden, embt, x, rnnB);
  k_gates<<<512, 256, 0, stream>>>(rnnB, W_ih, W_hh, ws + WS_GP);
  k_lstm<<<256, 256, 0, stream>>>(ws + WS_GP, b_ih, b_hh, cell, out_h, out_c, hB);
  k_fc<<<500, 256, 0, stream>>>(hB, fc_W, fc_b, preds);
}

// Round 11
// 149.209 us; speedup vs baseline: 2.1355x; 1.0088x over previous
//
#include <hip/hip_runtime.h>

#define S_LEN 512
#define BATCH 64
#define HDIM  1024
#define TWOH  2048
#define EMB   512
#define KDIM  2560      // 2H + EMB
#define KTOT  3584      // 2H + EMB + H
#define VOUT  32000

// ws layout (float offsets)
#define WS_MS    64
#define WS_CTX   2112                        // f32 [64][16][2048] = 2,097,152 floats
#define WS_GP    WS_CTX                      // gate partials [8][4096][64] f32 — aliases dead ctx
#define WS_RNNB  (WS_CTX + 64*16*2048)       // bf16 [64][3584] = 114,688 floats
#define WS_HB16  (WS_RNNB + 114688)          // bf16 [64][1024] = 32,768 floats

typedef __attribute__((ext_vector_type(8))) short bf16x8;
typedef __attribute__((ext_vector_type(4))) float f32x4;

__device__ __forceinline__ float sigmoidf_(float x) { return 1.f/(1.f+__expf(-x)); }

// RNE float -> bf16 (finite inputs)
__device__ __forceinline__ unsigned short f2bf(float f) {
  union { float f; unsigned u; } v; v.f = f;
  return (unsigned short)((v.u + 0x7fffu + ((v.u >> 16) & 1u)) >> 16);
}

__device__ __forceinline__ bf16x8 cvt_frag(const float4& a, const float4& b) {
  bf16x8 r;
  r[0] = (short)f2bf(a.x); r[1] = (short)f2bf(a.y);
  r[2] = (short)f2bf(a.z); r[3] = (short)f2bf(a.w);
  r[4] = (short)f2bf(b.x); r[5] = (short)f2bf(b.y);
  r[6] = (short)f2bf(b.z); r[7] = (short)f2bf(b.w);
  return r;
}

// K1 v3: single-pass online-softmax context, row-pipelined, hb inline.
__global__ __launch_bounds__(256) void k_attn(const float* __restrict__ enc,
                                              const float* __restrict__ eW,
                                              const float* __restrict__ eb,
                                              const float* __restrict__ hidden,
                                              float* __restrict__ ws_ms,
                                              float* __restrict__ ws_ctx) {
  __shared__ float lds_ms[4][2];
  __shared__ float lds_ctx[4][2048];
  const int lane  = threadIdx.x & 63;
  const int wave  = threadIdx.x >> 6;
  const int chunk = blockIdx.x;   // 0..15
  const int b     = blockIdx.y;   // 0..63

  float hba = 0.f;
  for (int k = lane; k < HDIM; k += 64) hba += hidden[b*HDIM + k] * eW[k];
#pragma unroll
  for (int st = 32; st >= 1; st >>= 1) hba += __shfl_xor(hba, st, 64);
  const float hb = hba + eb[0];

  float4 w4[8];
#pragma unroll
  for (int k = 0; k < 8; ++k)
    w4[k] = *reinterpret_cast<const float4*>(eW + HDIM + 4*lane + 256*k);

  const int s0 = chunk*32 + wave*8;
  const float* base = enc + ((size_t)(s0*BATCH + b))*TWOH + 4*lane;

  float m = 0.f, ssum = 0.f;      // relu => e >= 0
  float4 ctx[8];
#pragma unroll
  for (int k = 0; k < 8; ++k) ctx[k] = make_float4(0.f, 0.f, 0.f, 0.f);

  float4 va[8], vb[8];
#pragma unroll
  for (int k = 0; k < 8; ++k) va[k] = *reinterpret_cast<const float4*>(base + 256*k);

#define ATTN_STEP(VCUR, VNXT, I)                                              \
  {                                                                           \
    if ((I) < 7) {                                                            \
      const float* pn = base + (size_t)((I)+1)*BATCH*TWOH;                    \
      _Pragma("unroll")                                                       \
      for (int k = 0; k < 8; ++k)                                             \
        VNXT[k] = *reinterpret_cast<const float4*>(pn + 256*k);               \
    }                                                                         \
    float a = 0.f;                                                            \
    _Pragma("unroll")                                                         \
    for (int k = 0; k < 8; ++k)                                               \
      a += VCUR[k].x*w4[k].x + VCUR[k].y*w4[k].y +                            \
           VCUR[k].z*w4[k].z + VCUR[k].w*w4[k].w;                             \
    _Pragma("unroll")                                                         \
    for (int st = 1; st < 64; st <<= 1) a += __shfl_xor(a, st, 64);           \
    const float e = fmaxf(a + hb, 0.f);                                       \
    if (e > m) {                                                              \
      const float sc = __expf(m - e);                                         \
      ssum = ssum*sc + 1.f;                                                   \
      _Pragma("unroll")                                                       \
      for (int k = 0; k < 8; ++k) {                                           \
        ctx[k].x = fmaf(ctx[k].x, sc, VCUR[k].x);                             \
        ctx[k].y = fmaf(ctx[k].y, sc, VCUR[k].y);                             \
        ctx[k].z = fmaf(ctx[k].z, sc, VCUR[k].z);                             \
        ctx[k].w = fmaf(ctx[k].w, sc, VCUR[k].w);                             \
      }                                                                       \
      m = e;                                                                  \
    } else {                                                                  \
      const float pw = __expf(e - m);                                         \
      ssum += pw;                                                             \
      _Pragma("unroll")                                                       \
      for (int k = 0; k < 8; ++k) {                                           \
        ctx[k].x = fmaf(pw, VCUR[k].x, ctx[k].x);                             \
        ctx[k].y = fmaf(pw, VCUR[k].y, ctx[k].y);                             \
        ctx[k].z = fmaf(pw, VCUR[k].z, ctx[k].z);                             \
        ctx[k].w = fmaf(pw, VCUR[k].w, ctx[k].w);                             \
      }                                                                       \
    }                                                                         \
  }

  ATTN_STEP(va, vb, 0)
  ATTN_STEP(vb, va, 1)
  ATTN_STEP(va, vb, 2)
  ATTN_STEP(vb, va, 3)
  ATTN_STEP(va, vb, 4)
  ATTN_STEP(vb, va, 5)
  ATTN_STEP(va, vb, 6)
  ATTN_STEP(vb, va, 7)
#undef ATTN_STEP

  if (lane == 0) { lds_ms[wave][0] = m; lds_ms[wave][1] = ssum; }
  __syncthreads();
  const float M = fmaxf(fmaxf(lds_ms[0][0], lds_ms[1][0]),
                        fmaxf(lds_ms[2][0], lds_ms[3][0]));
  const float wsc = __expf(m - M);
  float ssum_c = 0.f;
#pragma unroll
  for (int w = 0; w < 4; ++w) ssum_c += __expf(lds_ms[w][0] - M) * lds_ms[w][1];
#pragma unroll
  for (int k = 0; k < 8; ++k) {
    float4 c = ctx[k];
    c.x *= wsc; c.y *= wsc; c.z *= wsc; c.w *= wsc;
    *reinterpret_cast<float4*>(&lds_ctx[wave][4*lane + 256*k]) = c;
  }
  __syncthreads();
  float* outp = ws_ctx + ((size_t)b*16 + chunk)*TWOH;
  for (int d = threadIdx.x; d < TWOH; d += 256)
    outp[d] = lds_ctx[0][d] + lds_ctx[1][d] + lds_ctx[2][d] + lds_ctx[3][d];
  if (threadIdx.x == 0) {
    ws_ms[((size_t)b*16 + chunk)*2]     = M;
    ws_ms[((size_t)b*16 + chunk)*2 + 1] = ssum_c;
  }
}

// K2 v3: combine 16 chunk-partials; emit bf16 rnnB [b][KTOT] = ctx | emb | hidden.
__global__ __launch_bounds__(256) void k_combine(const float* __restrict__ ws_ms,
                                                 const float* __restrict__ ws_ctx,
                                                 const float* __restrict__ hidden,
                                                 const float* __restrict__ emb_table,
                                                 const int* __restrict__ x,
                                                 unsigned short* __restrict__ rnnB) {
  const int b = blockIdx.x;
  float mc[16], sc[16];
#pragma unroll
  for (int c = 0; c < 16; ++c) {
    mc[c] = ws_ms[(b*16 + c)*2];
    sc[c] = ws_ms[(b*16 + c)*2 + 1];
  }
  float M = mc[0];
#pragma unroll
  for (int c = 1; c < 16; ++c) M = fmaxf(M, mc[c]);
  float wc[16], Ssum = 0.f;
#pragma unroll
  for (int c = 0; c < 16; ++c) { wc[c] = __expf(mc[c] - M); Ssum += wc[c]*sc[c]; }
  const float inv = 1.f / Ssum;
  unsigned short* rb = rnnB + (size_t)b*KTOT;
  for (int d = threadIdx.x; d < TWOH; d += 256) {
    float a = 0.f;
#pragma unroll
    for (int c = 0; c < 16; ++c) a += wc[c] * ws_ctx[((size_t)b*16 + c)*TWOH + d];
    rb[d] = f2bf(a * inv);
  }
  const int xb = x[b];
  for (int e = threadIdx.x; e < EMB; e += 256)
    rb[TWOH + e] = f2bf(emb_table[(size_t)xb*EMB + e]);
  for (int k = threadIdx.x; k < HDIM; k += 256)
    rb[KDIM + k] = f2bf(hidden[b*HDIM + k]);
}

// K3 v5: MFMA gate GEMM, k-loop unrolled x2 (64 k/iter, deeper load pipeline).
__global__ __launch_bounds__(256) void k_gates(const unsigned short* __restrict__ rnnB,
                                               const float* __restrict__ W_ih,
                                               const float* __restrict__ W_hh,
                                               float* __restrict__ ws_gp) {
  const int lane = threadIdx.x & 63;
  const int wave = threadIdx.x >> 6;
  const int part = blockIdx.x & 7;     // k-part: 448 each
  const int rg   = blockIdx.x >> 3;    // 0..63
  const int row0 = rg*64 + wave*16;
  const int mlo  = lane & 15;
  const int kg   = lane >> 4;
  const int j    = row0 + mlo;

  f32x4 acc0 = {0.f,0.f,0.f,0.f}, acc1 = acc0, acc2 = acc0, acc3 = acc0;

  for (int k0 = 0; k0 < 448; k0 += 64) {
    const int kb0 = part*448 + k0;
    const int kb1 = kb0 + 32;          // 32-chunks never cross KDIM (all %32==0)
    const float* ws0 = (kb0 < KDIM) ? (W_ih + (size_t)j*KDIM + kb0 + kg*8)
                                    : (W_hh + (size_t)j*HDIM + (kb0 - KDIM) + kg*8);
    const float* ws1 = (kb1 < KDIM) ? (W_ih + (size_t)j*KDIM + kb1 + kg*8)
                                    : (W_hh + (size_t)j*HDIM + (kb1 - KDIM) + kg*8);
    const float4 wa0 = *reinterpret_cast<const float4*>(ws0);
    const float4 wb0 = *reinterpret_cast<const float4*>(ws0 + 4);
    const float4 wa1 = *reinterpret_cast<const float4*>(ws1);
    const float4 wb1 = *reinterpret_cast<const float4*>(ws1 + 4);

    const size_t ko0 = (size_t)kb0 + kg*8;
    const size_t ko1 = (size_t)kb1 + kg*8;
    const unsigned short* rp0 = rnnB + (size_t)mlo*KTOT;
    const bf16x8 b00 = *reinterpret_cast<const bf16x8*>(rp0 + ko0);
    const bf16x8 b10 = *reinterpret_cast<const bf16x8*>(rp0 + 16*KTOT + ko0);
    const bf16x8 b20 = *reinterpret_cast<const bf16x8*>(rp0 + 32*KTOT + ko0);
    const bf16x8 b30 = *reinterpret_cast<const bf16x8*>(rp0 + 48*KTOT + ko0);
    const bf16x8 b01 = *reinterpret_cast<const bf16x8*>(rp0 + ko1);
    const bf16x8 b11 = *reinterpret_cast<const bf16x8*>(rp0 + 16*KTOT + ko1);
    const bf16x8 b21 = *reinterpret_cast<const bf16x8*>(rp0 + 32*KTOT + ko1);
    const bf16x8 b31 = *reinterpret_cast<const bf16x8*>(rp0 + 48*KTOT + ko1);

    const bf16x8 af0 = cvt_frag(wa0, wb0);
    const bf16x8 af1 = cvt_frag(wa1, wb1);

    acc0 = __builtin_amdgcn_mfma_f32_16x16x32_bf16(af0, b00, acc0, 0, 0, 0);
    acc1 = __builtin_amdgcn_mfma_f32_16x16x32_bf16(af0, b10, acc1, 0, 0, 0);
    acc2 = __builtin_amdgcn_mfma_f32_16x16x32_bf16(af0, b20, acc2, 0, 0, 0);
    acc3 = __builtin_amdgcn_mfma_f32_16x16x32_bf16(af0, b30, acc3, 0, 0, 0);
    acc0 = __builtin_amdgcn_mfma_f32_16x16x32_bf16(af1, b01, acc0, 0, 0, 0);
    acc1 = __builtin_amdgcn_mfma_f32_16x16x32_bf16(af1, b11, acc1, 0, 0, 0);
    acc2 = __builtin_amdgcn_mfma_f32_16x16x32_bf16(af1, b21, acc2, 0, 0, 0);
    acc3 = __builtin_amdgcn_mfma_f32_16x16x32_bf16(af1, b31, acc3, 0, 0, 0);
  }

  const int mbase = row0 + kg*4;
#define G_ST(ACC, N)                                                          \
  {                                                                           \
    _Pragma("unroll")                                                         \
    for (int jj = 0; jj < 4; ++jj)                                            \
      ws_gp[((size_t)part*4096 + mbase + jj)*64 + ((N)*16 + mlo)] = ACC[jj];  \
  }
  G_ST(acc0, 0) G_ST(acc1, 1) G_ST(acc2, 2) G_ST(acc3, 3)
#undef G_ST
}

// K3b: sum 8 partials + biases, LSTM pointwise; emit h as f32 outs + bf16 hB.
__global__ __launch_bounds__(256) void k_lstm(const float* __restrict__ ws_gp,
                                              const float* __restrict__ b_ih,
                                              const float* __restrict__ b_hh,
                                              const float* __restrict__ cell,
                                              float* __restrict__ out_h,
                                              float* __restrict__ out_c,
                                              unsigned short* __restrict__ hB) {
  const int id = blockIdx.x*256 + threadIdx.x;  // 65536
  const int h = id >> 6, b = id & 63;
  float g[4];
#pragma unroll
  for (int gg = 0; gg < 4; ++gg) {
    const int j = gg*1024 + h;
    float v = b_ih[j] + b_hh[j];
#pragma unroll
    for (int p = 0; p < 8; ++p) v += ws_gp[((size_t)p*4096 + j)*64 + b];
    g[gg] = v;
  }
  const float iv = sigmoidf_(g[0]);
  const float fv = sigmoidf_(g[1]);
  const float gv = tanhf(g[2]);
  const float ov = sigmoidf_(g[3]);
  const float cold = cell[b*HDIM + h];
  const float cn = fmaf(fv, cold, iv*gv);
  const float hn = ov * tanhf(cn);
  out_h[b*HDIM + h] = hn;
  out_c[b*HDIM + h] = cn;
  hB[(size_t)b*HDIM + h] = f2bf(hn);
}

// K4 v8: MFMA fc GEMM, k-loop unrolled x2 (64 k/iter).
__global__ __launch_bounds__(256) void k_fc(const unsigned short* __restrict__ hB,
                                            const float* __restrict__ fc_W,
                                            const float* __restrict__ fc_b,
                                            float* __restrict__ preds) {
  const int lane = threadIdx.x & 63;
  const int wave = threadIdx.x >> 6;
  const int row0 = (blockIdx.x*4 + wave)*16;   // grid 500 -> 32000 rows
  const int mlo  = lane & 15;
  const int kg   = lane >> 4;

  const float* wrow = fc_W + (size_t)(row0 + mlo)*HDIM + kg*8;
  const unsigned short* hp = hB + (size_t)mlo*HDIM + kg*8;

  f32x4 acc0 = {0.f,0.f,0.f,0.f}, acc1 = acc0, acc2 = acc0, acc3 = acc0;

  for (int k0 = 0; k0 < HDIM; k0 += 64) {
    const float4 wa0 = *reinterpret_cast<const float4*>(wrow + k0);
    const float4 wb0 = *reinterpret_cast<const float4*>(wrow + k0 + 4);
    const float4 wa1 = *reinterpret_cast<const float4*>(wrow + k0 + 32);
    const float4 wb1 = *reinterpret_cast<const float4*>(wrow + k0 + 36);

    const bf16x8 b00 = *reinterpret_cast<const bf16x8*>(hp + k0);
    const bf16x8 b10 = *reinterpret_cast<const bf16x8*>(hp + 16*HDIM + k0);
    const bf16x8 b20 = *reinterpret_cast<const bf16x8*>(hp + 32*HDIM + k0);
    const bf16x8 b30 = *reinterpret_cast<const bf16x8*>(hp + 48*HDIM + k0);
    const bf16x8 b01 = *reinterpret_cast<const bf16x8*>(hp + k0 + 32);
    const bf16x8 b11 = *reinterpret_cast<const bf16x8*>(hp + 16*HDIM + k0 + 32);
    const bf16x8 b21 = *reinterpret_cast<const bf16x8*>(hp + 32*HDIM + k0 + 32);
    const bf16x8 b31 = *reinterpret_cast<const bf16x8*>(hp + 48*HDIM + k0 + 32);

    const bf16x8 af0 = cvt_frag(wa0, wb0);
    const bf16x8 af1 = cvt_frag(wa1, wb1);

    acc0 = __builtin_amdgcn_mfma_f32_16x16x32_bf16(af0, b00, acc0, 0, 0, 0);
    acc1 = __builtin_amdgcn_mfma_f32_16x16x32_bf16(af0, b10, acc1, 0, 0, 0);
    acc2 = __builtin_amdgcn_mfma_f32_16x16x32_bf16(af0, b20, acc2, 0, 0, 0);
    acc3 = __builtin_amdgcn_mfma_f32_16x16x32_bf16(af0, b30, acc3, 0, 0, 0);
    acc0 = __builtin_amdgcn_mfma_f32_16x16x32_bf16(af1, b01, acc0, 0, 0, 0);
    acc1 = __builtin_amdgcn_mfma_f32_16x16x32_bf16(af1, b11, acc1, 0, 0, 0);
    acc2 = __builtin_amdgcn_mfma_f32_16x16x32_bf16(af1, b21, acc2, 0, 0, 0);
    acc3 = __builtin_amdgcn_mfma_f32_16x16x32_bf16(af1, b31, acc3, 0, 0, 0);
  }

  const int mbase = row0 + kg*4;
  const float4 bias = make_float4(fc_b[mbase], fc_b[mbase+1],
                                  fc_b[mbase+2], fc_b[mbase+3]);
#define FC_STORE(ACC, N)                                                      \
  {                                                                           \
    float4 st = make_float4(ACC[0] + bias.x, ACC[1] + bias.y,                 \
                            ACC[2] + bias.z, ACC[3] + bias.w);                \
    *reinterpret_cast<float4*>(preds + (size_t)((N)*16 + mlo)*VOUT + mbase) = st; \
  }
  FC_STORE(acc0, 0) FC_STORE(acc1, 1) FC_STORE(acc2, 2) FC_STORE(acc3, 3)
#undef FC_STORE
}

extern "C" void kernel_launch(void* const* d_in, const int* in_sizes, int n_in,
                              void* d_out, int out_size, void* d_ws, size_t ws_size,
                              hipStream_t stream) {
  const int*   x      = (const int*)  d_in[0];
  const float* enc    = (const float*)d_in[1];
  const float* hidden = (const float*)d_in[2];
  const float* cell   = (const float*)d_in[3];
  const float* embt   = (const float*)d_in[4];
  const float* eW     = (const float*)d_in[5];
  const float* eb     = (const float*)d_in[6];
  const float* W_ih   = (const float*)d_in[7];
  const float* W_hh   = (const float*)d_in[8];
  const float* b_ih   = (const float*)d_in[9];
  const float* b_hh   = (const float*)d_in[10];
  const float* fc_W   = (const float*)d_in[11];
  const float* fc_b   = (const float*)d_in[12];

  float* out   = (float*)d_out;
  float* preds = out;                              // 64*32000
  float* out_h = out + (size_t)BATCH*VOUT;         // 64*1024
  float* out_c = out_h + BATCH*HDIM;               // 64*1024
  float* ws    = (float*)d_ws;
  unsigned short* rnnB = (unsigned short*)(ws + WS_RNNB);
  unsigned short* hB   = (unsigned short*)(ws + WS_HB16);

  k_attn<<<dim3(16, 64), 256, 0, stream>>>(enc, eW, eb, hidden, ws + WS_MS, ws + WS_CTX);
  k_combine<<<64, 256, 0, stream>>>(ws + WS_MS, ws + WS_CTX, hidden, embt, x, rnnB);
  k_gates<<<512, 256, 0, stream>>>(rnnB, W_ih, W_hh, ws + WS_GP);
  k_lstm<<<256, 256, 0, stream>>>(ws + WS_GP, b_ih, b_hh, cell, out_h, out_c, hB);
  k_fc<<<500, 256, 0, stream>>>(hB, fc_W, fc_b, preds);
}